// Round 1
// baseline (5141.452 us; speedup 1.0000x reference)
//
#include <hip/hip_runtime.h>

// Problem constants (fixed by the reference)
constexpr int NN = 50000;   // nodes
constexpr int NE = 800000;  // edges
constexpr float EPS = 1e-5f;

// ---------------------------------------------------------------------------
// degree (with self loop) -> dinv = rsqrt(deg+1), computed in place
// ---------------------------------------------------------------------------
__global__ void deg_kernel(const int* __restrict__ dst, float* __restrict__ deg) {
    int e = blockIdx.x * 256 + threadIdx.x;
    if (e < NE) atomicAdd(&deg[dst[e]], 1.0f);
}

__global__ void dinv_kernel(float* __restrict__ deg) {
    int n = blockIdx.x * 256 + threadIdx.x;
    if (n < NN) deg[n] = rsqrtf(deg[n] + 1.0f);
}

// ---------------------------------------------------------------------------
// GEMM: U = (X @ W) * dinv[row]   X:[NN,128] W:[128,FOUT] U:[NN,FOUT]
// Tile: 64 rows x FOUT cols per block, 256 threads, K staged in 32-chunks.
// Xs padded to 33 (scalar LDS writes/reads -> conflict-free broadcast reads).
// ---------------------------------------------------------------------------
template<int FOUT>
__global__ __launch_bounds__(256) void gemm_scale_kernel(
    const float* __restrict__ X, const float* __restrict__ W,
    const float* __restrict__ dinv, float* __restrict__ U)
{
    constexpr int COLG = FOUT / 4;     // float4 column groups
    constexpr int ROWG = 256 / COLG;   // row groups
    constexpr int R    = 64 / ROWG;    // rows per thread
    __shared__ float Xs[64][33];
    __shared__ float Ws[32][FOUT];

    const int tid  = threadIdx.x;
    const int cg   = tid % COLG;
    const int rg   = tid / COLG;
    const int row0 = blockIdx.x * 64;

    float acc[R][4];
#pragma unroll
    for (int r = 0; r < R; r++) { acc[r][0]=0.f; acc[r][1]=0.f; acc[r][2]=0.f; acc[r][3]=0.f; }

    for (int k0 = 0; k0 < 128; k0 += 32) {
        // stage X tile: 64x32 floats = 512 float4 loads, 2 per thread
#pragma unroll
        for (int it = 0; it < 2; it++) {
            int idx = tid + it * 256;
            int r   = idx >> 3;
            int k4  = (idx & 7) * 4;
            float4 v = make_float4(0.f, 0.f, 0.f, 0.f);
            int row = row0 + r;
            if (row < NN) v = *(const float4*)&X[row * 128 + k0 + k4];
            Xs[r][k4 + 0] = v.x; Xs[r][k4 + 1] = v.y;
            Xs[r][k4 + 2] = v.z; Xs[r][k4 + 3] = v.w;
        }
        // stage W tile: 32xFOUT floats
#pragma unroll
        for (int it = 0; it < FOUT / 32; it++) {
            int idx = tid + it * 256;
            int kk  = idx / COLG;
            int c4  = (idx % COLG) * 4;
            *(float4*)&Ws[kk][c4] = *(const float4*)&W[(k0 + kk) * FOUT + c4];
        }
        __syncthreads();
#pragma unroll
        for (int kk = 0; kk < 32; kk++) {
            float wv[4];
            *(float4*)wv = *(const float4*)&Ws[kk][cg * 4];
#pragma unroll
            for (int r = 0; r < R; r++) {
                float xv = Xs[rg * R + r][kk];
                acc[r][0] += xv * wv[0];
                acc[r][1] += xv * wv[1];
                acc[r][2] += xv * wv[2];
                acc[r][3] += xv * wv[3];
            }
        }
        __syncthreads();
    }
#pragma unroll
    for (int r = 0; r < R; r++) {
        int row = row0 + rg * R + r;
        if (row < NN) {
            float di = dinv[row];
            float4 o = make_float4(acc[r][0] * di, acc[r][1] * di,
                                   acc[r][2] * di, acc[r][3] * di);
            *(float4*)&U[row * FOUT + cg * 4] = o;
        }
    }
}

// ---------------------------------------------------------------------------
// Edge scatter: AGG[dst] += U[src]  (unweighted; dinv factors applied outside)
// F/4 threads per edge, float4 read + 4 scalar atomics.
// ---------------------------------------------------------------------------
template<int F>
__global__ void scatter_kernel(const int* __restrict__ src, const int* __restrict__ dst,
                               const float* __restrict__ U, float* __restrict__ AGG)
{
    constexpr int TPE = F / 4;
    int t  = blockIdx.x * 256 + threadIdx.x;
    int e  = t / TPE;
    if (e >= NE) return;
    int fg = (t % TPE) * 4;
    int s = src[e], d = dst[e];
    float4 v = *(const float4*)&U[s * F + fg];
    float* a = &AGG[d * F + fg];
    atomicAdd(a + 0, v.x);
    atomicAdd(a + 1, v.y);
    atomicAdd(a + 2, v.z);
    atomicAdd(a + 3, v.w);
}

// ---------------------------------------------------------------------------
// Y = (AGG + U) * dinv[row] + b  (in place on AGG), + per-column sum/sumsq
// blockDim = 128, thread owns one column; rows strided over grid.
// ---------------------------------------------------------------------------
__global__ __launch_bounds__(128) void finish_stats_kernel(
    float* __restrict__ AGG, const float* __restrict__ U,
    const float* __restrict__ dinv, const float* __restrict__ b,
    float* __restrict__ sums, float* __restrict__ sumsq)
{
    int col = threadIdx.x;
    float bias = b[col];
    float ls = 0.f, lq = 0.f;
    for (int row = blockIdx.x; row < NN; row += gridDim.x) {
        int i = row * 128 + col;
        float y = (AGG[i] + U[i]) * dinv[row] + bias;
        AGG[i] = y;
        ls += y;
        lq += y * y;
    }
    atomicAdd(&sums[col], ls);
    atomicAdd(&sumsq[col], lq);
}

// sums/sumsq -> scale/shift (in place)
__global__ void bn_prep_kernel(float* __restrict__ sums, float* __restrict__ sumsq,
                               const float* __restrict__ g, const float* __restrict__ be)
{
    int c = threadIdx.x;
    float mu  = sums[c] * (1.0f / NN);
    float var = sumsq[c] * (1.0f / NN) - mu * mu;
    float sc  = rsqrtf(var + EPS) * g[c];
    sums[c]  = sc;
    sumsq[c] = be[c] - mu * sc;
}

// X2 = relu(Y * scale + shift), float4 elementwise
__global__ void bn_relu_kernel(const float* __restrict__ Y, float* __restrict__ X2,
                               const float* __restrict__ scale, const float* __restrict__ shift)
{
    int i4 = blockIdx.x * 256 + threadIdx.x;
    if (i4 >= NN * 32) return;           // NN*128/4
    int c0 = (i4 & 31) * 4;
    float4 y = ((const float4*)Y)[i4];
    float4 o;
    o.x = fmaxf(0.f, y.x * scale[c0 + 0] + shift[c0 + 0]);
    o.y = fmaxf(0.f, y.y * scale[c0 + 1] + shift[c0 + 1]);
    o.z = fmaxf(0.f, y.z * scale[c0 + 2] + shift[c0 + 2]);
    o.w = fmaxf(0.f, y.w * scale[c0 + 3] + shift[c0 + 3]);
    ((float4*)X2)[i4] = o;
}

// final layer epilogue: OUT = (OUT_agg + U) * dinv[row] + b4, F=64, in place
__global__ void finish_out_kernel(float* __restrict__ OUTP, const float* __restrict__ U,
                                  const float* __restrict__ dinv, const float* __restrict__ b)
{
    int i4 = blockIdx.x * 256 + threadIdx.x;
    if (i4 >= NN * 16) return;           // NN*64/4
    int row = i4 >> 4;
    int c0  = (i4 & 15) * 4;
    float4 a = ((const float4*)OUTP)[i4];
    float4 u = ((const float4*)U)[i4];
    float di = dinv[row];
    float4 o;
    o.x = (a.x + u.x) * di + b[c0 + 0];
    o.y = (a.y + u.y) * di + b[c0 + 1];
    o.z = (a.z + u.z) * di + b[c0 + 2];
    o.w = (a.w + u.w) * di + b[c0 + 3];
    ((float4*)OUTP)[i4] = o;
}

// ---------------------------------------------------------------------------
extern "C" void kernel_launch(void* const* d_in, const int* in_sizes, int n_in,
                              void* d_out, int out_size, void* d_ws, size_t ws_size,
                              hipStream_t stream)
{
    const float* x   = (const float*)d_in[0];
    const int*   ei  = (const int*)d_in[1];
    const int*   src = ei;
    const int*   dst = ei + NE;
    const float* W1 = (const float*)d_in[2];  const float* b1 = (const float*)d_in[3];
    const float* W2 = (const float*)d_in[4];  const float* b2 = (const float*)d_in[5];
    const float* W3 = (const float*)d_in[6];  const float* b3 = (const float*)d_in[7];
    const float* W4 = (const float*)d_in[8];  const float* b4 = (const float*)d_in[9];
    const float* g1 = (const float*)d_in[10]; const float* be1 = (const float*)d_in[11];
    const float* g2 = (const float*)d_in[12]; const float* be2 = (const float*)d_in[13];
    const float* g3 = (const float*)d_in[14]; const float* be3 = (const float*)d_in[15];
    float* out = (float*)d_out;

    float* ws    = (float*)d_ws;
    float* dinv  = ws;                 // NN
    float* sums  = ws + NN;            // 128
    float* sumsq = sums + 128;         // 128
    float* A     = sumsq + 128;        // NN*128
    float* B     = A + (size_t)NN * 128; // NN*128

    const size_t bigBytes = (size_t)NN * 128 * sizeof(float);

    // degrees -> dinv
    hipMemsetAsync(dinv, 0, NN * sizeof(float), stream);
    deg_kernel<<<(NE + 255) / 256, 256, 0, stream>>>(dst, dinv);
    dinv_kernel<<<(NN + 255) / 256, 256, 0, stream>>>(dinv);

    const int gemmGrid  = (NN + 63) / 64;
    const int scat128   = (NE * 32 + 255) / 256;
    const int scat64    = (NE * 16 + 255) / 256;
    const int eltGrid   = (NN * 32 + 255) / 256;

    // ---- Layer 1: x -> A(U) -> B(agg->Y) -> A(X2)
    gemm_scale_kernel<128><<<gemmGrid, 256, 0, stream>>>(x, W1, dinv, A);
    hipMemsetAsync(B, 0, bigBytes, stream);
    hipMemsetAsync(sums, 0, 256 * sizeof(float), stream);
    scatter_kernel<128><<<scat128, 256, 0, stream>>>(src, dst, A, B);
    finish_stats_kernel<<<960, 128, 0, stream>>>(B, A, dinv, b1, sums, sumsq);
    bn_prep_kernel<<<1, 128, 0, stream>>>(sums, sumsq, g1, be1);
    bn_relu_kernel<<<eltGrid, 256, 0, stream>>>(B, A, sums, sumsq);

    // ---- Layer 2: A -> B(U) -> A(agg->Y) -> B(X3)
    gemm_scale_kernel<128><<<gemmGrid, 256, 0, stream>>>(A, W2, dinv, B);
    hipMemsetAsync(A, 0, bigBytes, stream);
    hipMemsetAsync(sums, 0, 256 * sizeof(float), stream);
    scatter_kernel<128><<<scat128, 256, 0, stream>>>(src, dst, B, A);
    finish_stats_kernel<<<960, 128, 0, stream>>>(A, B, dinv, b2, sums, sumsq);
    bn_prep_kernel<<<1, 128, 0, stream>>>(sums, sumsq, g2, be2);
    bn_relu_kernel<<<eltGrid, 256, 0, stream>>>(A, B, sums, sumsq);

    // ---- Layer 3: B -> A(U) -> B(agg->Y) -> A(X4)
    gemm_scale_kernel<128><<<gemmGrid, 256, 0, stream>>>(B, W3, dinv, A);
    hipMemsetAsync(B, 0, bigBytes, stream);
    hipMemsetAsync(sums, 0, 256 * sizeof(float), stream);
    scatter_kernel<128><<<scat128, 256, 0, stream>>>(src, dst, A, B);
    finish_stats_kernel<<<960, 128, 0, stream>>>(B, A, dinv, b3, sums, sumsq);
    bn_prep_kernel<<<1, 128, 0, stream>>>(sums, sumsq, g3, be3);
    bn_relu_kernel<<<eltGrid, 256, 0, stream>>>(B, A, sums, sumsq);

    // ---- Layer 4: A -> B(U64, first NN*64 floats) -> d_out
    gemm_scale_kernel<64><<<gemmGrid, 256, 0, stream>>>(A, W4, dinv, B);
    hipMemsetAsync(out, 0, (size_t)NN * 64 * sizeof(float), stream);
    scatter_kernel<64><<<scat64, 256, 0, stream>>>(src, dst, B, out);
    finish_out_kernel<<<(NN * 16 + 255) / 256, 256, 0, stream>>>(out, B, dinv, b4);
}

// Round 2
// 667.353 us; speedup vs baseline: 7.7042x; 7.7042x over previous
//
#include <hip/hip_runtime.h>

// Problem constants (fixed by the reference)
constexpr int NN = 50000;   // nodes
constexpr int NE = 800000;  // edges
constexpr float EPS = 1e-5f;

constexpr int SCAN_BS  = 256;
constexpr int SCAN_NB  = (NN + SCAN_BS - 1) / SCAN_BS;   // 196

// ---------------------------------------------------------------------------
// CSR build: histogram -> scan -> fill
// ---------------------------------------------------------------------------
__global__ void hist_kernel(const int* __restrict__ dst, int* __restrict__ counts) {
    int e = blockIdx.x * 256 + threadIdx.x;
    if (e < NE) atomicAdd(&counts[dst[e]], 1);
}

__global__ __launch_bounds__(SCAN_BS) void blocksum_kernel(const int* __restrict__ counts,
                                                           int* __restrict__ bsum) {
    __shared__ int s[SCAN_BS];
    int t = threadIdx.x;
    int i = blockIdx.x * SCAN_BS + t;
    s[t] = (i < NN) ? counts[i] : 0;
    __syncthreads();
    for (int off = SCAN_BS / 2; off > 0; off >>= 1) {
        if (t < off) s[t] += s[t + off];
        __syncthreads();
    }
    if (t == 0) bsum[blockIdx.x] = s[0];
}

__global__ __launch_bounds__(SCAN_BS) void scanbsum_kernel(int* __restrict__ bsum) {
    __shared__ int s[SCAN_BS];
    int t = threadIdx.x;
    int v = (t < SCAN_NB) ? bsum[t] : 0;
    s[t] = v;
    __syncthreads();
    for (int off = 1; off < SCAN_BS; off <<= 1) {
        int x = (t >= off) ? s[t - off] : 0;
        __syncthreads();
        s[t] += x;
        __syncthreads();
    }
    if (t < SCAN_NB) bsum[t] = s[t] - v;   // exclusive
}

__global__ __launch_bounds__(SCAN_BS) void scanfinal_kernel(const int* __restrict__ counts,
                                                            const int* __restrict__ bsum,
                                                            int* __restrict__ rowstart) {
    __shared__ int s[SCAN_BS];
    int t = threadIdx.x;
    int i = blockIdx.x * SCAN_BS + t;
    int c = (i < NN) ? counts[i] : 0;
    s[t] = c;
    __syncthreads();
    for (int off = 1; off < SCAN_BS; off <<= 1) {
        int x = (t >= off) ? s[t - off] : 0;
        __syncthreads();
        s[t] += x;
        __syncthreads();
    }
    if (i < NN) rowstart[i] = s[t] - c + bsum[blockIdx.x];
}

__global__ void fill_kernel(const int* __restrict__ src, const int* __restrict__ dst,
                            const int* __restrict__ rowstart, int* __restrict__ cursor,
                            int* __restrict__ csr) {
    int e = blockIdx.x * 256 + threadIdx.x;
    if (e >= NE) return;
    int d = dst[e];
    int pos = rowstart[d] + atomicAdd(&cursor[d], 1);
    csr[pos] = src[e];
}

__global__ void dinv_kernel(const int* __restrict__ counts, float* __restrict__ dinv) {
    int n = blockIdx.x * 256 + threadIdx.x;
    if (n < NN) dinv[n] = rsqrtf((float)counts[n] + 1.0f);
}

// ---------------------------------------------------------------------------
// GEMM: U = (X @ W) * dinv[row]   X:[NN,128] W:[128,FOUT] U:[NN,FOUT]
// ---------------------------------------------------------------------------
template<int FOUT>
__global__ __launch_bounds__(256) void gemm_scale_kernel(
    const float* __restrict__ X, const float* __restrict__ W,
    const float* __restrict__ dinv, float* __restrict__ U)
{
    constexpr int COLG = FOUT / 4;     // float4 column groups
    constexpr int ROWG = 256 / COLG;   // row groups
    constexpr int R    = 64 / ROWG;    // rows per thread
    __shared__ float Xs[64][33];
    __shared__ float Ws[32][FOUT];

    const int tid  = threadIdx.x;
    const int cg   = tid % COLG;
    const int rg   = tid / COLG;
    const int row0 = blockIdx.x * 64;

    float acc[R][4];
#pragma unroll
    for (int r = 0; r < R; r++) { acc[r][0]=0.f; acc[r][1]=0.f; acc[r][2]=0.f; acc[r][3]=0.f; }

    for (int k0 = 0; k0 < 128; k0 += 32) {
#pragma unroll
        for (int it = 0; it < 2; it++) {
            int idx = tid + it * 256;
            int r   = idx >> 3;
            int k4  = (idx & 7) * 4;
            float4 v = make_float4(0.f, 0.f, 0.f, 0.f);
            int row = row0 + r;
            if (row < NN) v = *(const float4*)&X[row * 128 + k0 + k4];
            Xs[r][k4 + 0] = v.x; Xs[r][k4 + 1] = v.y;
            Xs[r][k4 + 2] = v.z; Xs[r][k4 + 3] = v.w;
        }
#pragma unroll
        for (int it = 0; it < FOUT / 32; it++) {
            int idx = tid + it * 256;
            int kk  = idx / COLG;
            int c4  = (idx % COLG) * 4;
            *(float4*)&Ws[kk][c4] = *(const float4*)&W[(k0 + kk) * FOUT + c4];
        }
        __syncthreads();
#pragma unroll
        for (int kk = 0; kk < 32; kk++) {
            float wv[4];
            *(float4*)wv = *(const float4*)&Ws[kk][cg * 4];
#pragma unroll
            for (int r = 0; r < R; r++) {
                float xv = Xs[rg * R + r][kk];
                acc[r][0] += xv * wv[0];
                acc[r][1] += xv * wv[1];
                acc[r][2] += xv * wv[2];
                acc[r][3] += xv * wv[3];
            }
        }
        __syncthreads();
    }
#pragma unroll
    for (int r = 0; r < R; r++) {
        int row = row0 + rg * R + r;
        if (row < NN) {
            float di = dinv[row];
            float4 o = make_float4(acc[r][0] * di, acc[r][1] * di,
                                   acc[r][2] * di, acc[r][3] * di);
            *(float4*)&U[row * FOUT + cg * 4] = o;
        }
    }
}

// ---------------------------------------------------------------------------
// Gather aggregation (atomic-free): one wave per dst node.
// Y[n] = dinv[n] * (sum_{e->n} U[src] + U[n]) + b
// F=128: lane holds 2 cols (float2). F=64: lane holds 1 col.
// ---------------------------------------------------------------------------
__global__ __launch_bounds__(256) void gather128_kernel(
    const int* __restrict__ csr, const int* __restrict__ rowstart,
    const int* __restrict__ counts, const float* __restrict__ U,
    const float* __restrict__ dinv, const float* __restrict__ b,
    float* __restrict__ Y)
{
    int n    = (blockIdx.x * 256 + threadIdx.x) >> 6;
    int lane = threadIdx.x & 63;
    if (n >= NN) return;
    int base = rowstart[n];
    int deg  = counts[n];
    float ax = 0.f, ay = 0.f;
    int j = 0;
    for (; j + 4 <= deg; j += 4) {
        int s0 = csr[base + j + 0];
        int s1 = csr[base + j + 1];
        int s2 = csr[base + j + 2];
        int s3 = csr[base + j + 3];
        float2 v0 = *(const float2*)&U[(size_t)s0 * 128 + lane * 2];
        float2 v1 = *(const float2*)&U[(size_t)s1 * 128 + lane * 2];
        float2 v2 = *(const float2*)&U[(size_t)s2 * 128 + lane * 2];
        float2 v3 = *(const float2*)&U[(size_t)s3 * 128 + lane * 2];
        ax += v0.x + v1.x + v2.x + v3.x;
        ay += v0.y + v1.y + v2.y + v3.y;
    }
    for (; j < deg; j++) {
        int s = csr[base + j];
        float2 v = *(const float2*)&U[(size_t)s * 128 + lane * 2];
        ax += v.x; ay += v.y;
    }
    float2 u = *(const float2*)&U[(size_t)n * 128 + lane * 2];
    float di = dinv[n];
    float2 o;
    o.x = di * (ax + u.x) + b[lane * 2 + 0];
    o.y = di * (ay + u.y) + b[lane * 2 + 1];
    *(float2*)&Y[(size_t)n * 128 + lane * 2] = o;
}

__global__ __launch_bounds__(256) void gather64_kernel(
    const int* __restrict__ csr, const int* __restrict__ rowstart,
    const int* __restrict__ counts, const float* __restrict__ U,
    const float* __restrict__ dinv, const float* __restrict__ b,
    float* __restrict__ Y)
{
    int n    = (blockIdx.x * 256 + threadIdx.x) >> 6;
    int lane = threadIdx.x & 63;
    if (n >= NN) return;
    int base = rowstart[n];
    int deg  = counts[n];
    float a = 0.f;
    int j = 0;
    for (; j + 4 <= deg; j += 4) {
        int s0 = csr[base + j + 0];
        int s1 = csr[base + j + 1];
        int s2 = csr[base + j + 2];
        int s3 = csr[base + j + 3];
        a += U[(size_t)s0 * 64 + lane] + U[(size_t)s1 * 64 + lane]
           + U[(size_t)s2 * 64 + lane] + U[(size_t)s3 * 64 + lane];
    }
    for (; j < deg; j++) {
        int s = csr[base + j];
        a += U[(size_t)s * 64 + lane];
    }
    float u = U[(size_t)n * 64 + lane];
    Y[(size_t)n * 64 + lane] = dinv[n] * (a + u) + b[lane];
}

// ---------------------------------------------------------------------------
// BN: per-column sums (read-only) -> scale/shift -> fused scale+shift+relu
// ---------------------------------------------------------------------------
__global__ __launch_bounds__(128) void stats_kernel(const float* __restrict__ Y,
                                                    float* __restrict__ sums,
                                                    float* __restrict__ sumsq)
{
    int col = threadIdx.x;
    float ls = 0.f, lq = 0.f;
    for (int row = blockIdx.x; row < NN; row += gridDim.x) {
        float y = Y[(size_t)row * 128 + col];
        ls += y;
        lq += y * y;
    }
    atomicAdd(&sums[col], ls);
    atomicAdd(&sumsq[col], lq);
}

__global__ void bn_prep_kernel(float* __restrict__ sums, float* __restrict__ sumsq,
                               const float* __restrict__ g, const float* __restrict__ be)
{
    int c = threadIdx.x;
    float mu  = sums[c] * (1.0f / NN);
    float var = sumsq[c] * (1.0f / NN) - mu * mu;
    float sc  = rsqrtf(var + EPS) * g[c];
    sums[c]  = sc;
    sumsq[c] = be[c] - mu * sc;
}

__global__ void bn_relu_kernel(float* __restrict__ Y,
                               const float* __restrict__ scale,
                               const float* __restrict__ shift)
{
    int i4 = blockIdx.x * 256 + threadIdx.x;
    if (i4 >= NN * 32) return;           // NN*128/4
    int c0 = (i4 & 31) * 4;
    float4 y = ((const float4*)Y)[i4];
    float4 o;
    o.x = fmaxf(0.f, y.x * scale[c0 + 0] + shift[c0 + 0]);
    o.y = fmaxf(0.f, y.y * scale[c0 + 1] + shift[c0 + 1]);
    o.z = fmaxf(0.f, y.z * scale[c0 + 2] + shift[c0 + 2]);
    o.w = fmaxf(0.f, y.w * scale[c0 + 3] + shift[c0 + 3]);
    ((float4*)Y)[i4] = o;
}

// ---------------------------------------------------------------------------
extern "C" void kernel_launch(void* const* d_in, const int* in_sizes, int n_in,
                              void* d_out, int out_size, void* d_ws, size_t ws_size,
                              hipStream_t stream)
{
    const float* x   = (const float*)d_in[0];
    const int*   ei  = (const int*)d_in[1];
    const int*   src = ei;
    const int*   dst = ei + NE;
    const float* W1 = (const float*)d_in[2];  const float* b1 = (const float*)d_in[3];
    const float* W2 = (const float*)d_in[4];  const float* b2 = (const float*)d_in[5];
    const float* W3 = (const float*)d_in[6];  const float* b3 = (const float*)d_in[7];
    const float* W4 = (const float*)d_in[8];  const float* b4 = (const float*)d_in[9];
    const float* g1 = (const float*)d_in[10]; const float* be1 = (const float*)d_in[11];
    const float* g2 = (const float*)d_in[12]; const float* be2 = (const float*)d_in[13];
    const float* g3 = (const float*)d_in[14]; const float* be3 = (const float*)d_in[15];
    float* out = (float*)d_out;

    // workspace layout (~52 MB)
    float* ws      = (float*)d_ws;
    float* dinv    = ws;                        // NN floats
    int*   counts  = (int*)(ws + NN);           // NN ints
    int*   rowst   = counts + NN;               // NN ints
    int*   cursor  = rowst + NN;                // NN ints
    int*   bsum    = cursor + NN;               // 256 ints
    float* sums    = (float*)(bsum + 256);      // 128
    float* sumsq   = sums + 128;                // 128
    float* A       = sumsq + 128;               // NN*128
    float* B       = A + (size_t)NN * 128;      // NN*128

    // csr_src lives in d_out for layers 1-3 (3.2 MB of 12.8 MB)
    int* csr  = (int*)d_out;
    int* csr4 = (int*)(B + (size_t)NN * 64);    // relocated for layer 4

    const int edgeGrid = (NE + 255) / 256;
    const int gemmGrid = (NN + 63) / 64;
    const int gathGrid = (NN * 64 + 255) / 256;   // wave per node
    const int eltGrid  = (NN * 32 + 255) / 256;

    // ---- CSR build + dinv
    hipMemsetAsync(counts, 0, NN * sizeof(int), stream);
    hipMemsetAsync(cursor, 0, NN * sizeof(int), stream);
    hist_kernel<<<edgeGrid, 256, 0, stream>>>(dst, counts);
    blocksum_kernel<<<SCAN_NB, SCAN_BS, 0, stream>>>(counts, bsum);
    scanbsum_kernel<<<1, SCAN_BS, 0, stream>>>(bsum);
    scanfinal_kernel<<<SCAN_NB, SCAN_BS, 0, stream>>>(counts, bsum, rowst);
    fill_kernel<<<edgeGrid, 256, 0, stream>>>(src, dst, rowst, cursor, csr);
    dinv_kernel<<<(NN + 255) / 256, 256, 0, stream>>>(counts, dinv);

    // ---- Layer 1: x -> B(U) -> A(Y) -> A(X2 in place)
    gemm_scale_kernel<128><<<gemmGrid, 256, 0, stream>>>(x, W1, dinv, B);
    gather128_kernel<<<gathGrid, 256, 0, stream>>>(csr, rowst, counts, B, dinv, b1, A);
    hipMemsetAsync(sums, 0, 256 * sizeof(float), stream);
    stats_kernel<<<960, 128, 0, stream>>>(A, sums, sumsq);
    bn_prep_kernel<<<1, 128, 0, stream>>>(sums, sumsq, g1, be1);
    bn_relu_kernel<<<eltGrid, 256, 0, stream>>>(A, sums, sumsq);

    // ---- Layer 2
    gemm_scale_kernel<128><<<gemmGrid, 256, 0, stream>>>(A, W2, dinv, B);
    gather128_kernel<<<gathGrid, 256, 0, stream>>>(csr, rowst, counts, B, dinv, b2, A);
    hipMemsetAsync(sums, 0, 256 * sizeof(float), stream);
    stats_kernel<<<960, 128, 0, stream>>>(A, sums, sumsq);
    bn_prep_kernel<<<1, 128, 0, stream>>>(sums, sumsq, g2, be2);
    bn_relu_kernel<<<eltGrid, 256, 0, stream>>>(A, sums, sumsq);

    // ---- Layer 3
    gemm_scale_kernel<128><<<gemmGrid, 256, 0, stream>>>(A, W3, dinv, B);
    gather128_kernel<<<gathGrid, 256, 0, stream>>>(csr, rowst, counts, B, dinv, b3, A);
    hipMemsetAsync(sums, 0, 256 * sizeof(float), stream);
    stats_kernel<<<960, 128, 0, stream>>>(A, sums, sumsq);
    bn_prep_kernel<<<1, 128, 0, stream>>>(sums, sumsq, g3, be3);
    bn_relu_kernel<<<eltGrid, 256, 0, stream>>>(A, sums, sumsq);

    // ---- Layer 4: A -> B(U64) ; relocate csr out of d_out; gather -> d_out
    gemm_scale_kernel<64><<<gemmGrid, 256, 0, stream>>>(A, W4, dinv, B);
    hipMemcpyAsync(csr4, csr, NE * sizeof(int), hipMemcpyDeviceToDevice, stream);
    gather64_kernel<<<gathGrid, 256, 0, stream>>>(csr4, rowst, counts, B, dinv, b4, out);
}

// Round 3
// 528.083 us; speedup vs baseline: 9.7361x; 1.2637x over previous
//
#include <hip/hip_runtime.h>

// Problem constants (fixed by the reference)
constexpr int NN = 50000;   // nodes
constexpr int NE = 800000;  // edges
constexpr float EPS = 1e-5f;

constexpr int SCAN_BS  = 256;
constexpr int SCAN_NB  = (NN + SCAN_BS - 1) / SCAN_BS;   // 196

typedef short bf16x8 __attribute__((ext_vector_type(8)));
typedef float f32x4  __attribute__((ext_vector_type(4)));

// float -> bf16 bits (RNE, finite values)
__device__ __forceinline__ ushort f2bf(float x) {
    union { float f; unsigned u; } a; a.f = x;
    unsigned u = a.u;
    unsigned r = (u + 0x7FFFu + ((u >> 16) & 1u)) >> 16;
    return (ushort)r;
}
// bf16 bits (low 16 of uint) -> float
__device__ __forceinline__ float bflo(unsigned p) {
    union { unsigned u; float f; } a; a.u = p << 16; return a.f;
}
__device__ __forceinline__ float bfhi(unsigned p) {
    union { unsigned u; float f; } a; a.u = p & 0xFFFF0000u; return a.f;
}

// ---------------------------------------------------------------------------
// CSR build: histogram -> scan -> fill
// ---------------------------------------------------------------------------
__global__ void hist_kernel(const int* __restrict__ dst, int* __restrict__ counts) {
    int e = blockIdx.x * 256 + threadIdx.x;
    if (e < NE) atomicAdd(&counts[dst[e]], 1);
}

__global__ __launch_bounds__(SCAN_BS) void blocksum_kernel(const int* __restrict__ counts,
                                                           int* __restrict__ bsum) {
    __shared__ int s[SCAN_BS];
    int t = threadIdx.x;
    int i = blockIdx.x * SCAN_BS + t;
    s[t] = (i < NN) ? counts[i] : 0;
    __syncthreads();
    for (int off = SCAN_BS / 2; off > 0; off >>= 1) {
        if (t < off) s[t] += s[t + off];
        __syncthreads();
    }
    if (t == 0) bsum[blockIdx.x] = s[0];
}

__global__ __launch_bounds__(SCAN_BS) void scanbsum_kernel(int* __restrict__ bsum) {
    __shared__ int s[SCAN_BS];
    int t = threadIdx.x;
    int v = (t < SCAN_NB) ? bsum[t] : 0;
    s[t] = v;
    __syncthreads();
    for (int off = 1; off < SCAN_BS; off <<= 1) {
        int x = (t >= off) ? s[t - off] : 0;
        __syncthreads();
        s[t] += x;
        __syncthreads();
    }
    if (t < SCAN_NB) bsum[t] = s[t] - v;   // exclusive
}

__global__ __launch_bounds__(SCAN_BS) void scanfinal_kernel(const int* __restrict__ counts,
                                                            const int* __restrict__ bsum,
                                                            int* __restrict__ rowstart) {
    __shared__ int s[SCAN_BS];
    int t = threadIdx.x;
    int i = blockIdx.x * SCAN_BS + t;
    int c = (i < NN) ? counts[i] : 0;
    s[t] = c;
    __syncthreads();
    for (int off = 1; off < SCAN_BS; off <<= 1) {
        int x = (t >= off) ? s[t - off] : 0;
        __syncthreads();
        s[t] += x;
        __syncthreads();
    }
    if (i < NN) rowstart[i] = s[t] - c + bsum[blockIdx.x];
}

__global__ void fill_kernel(const int* __restrict__ src, const int* __restrict__ dst,
                            const int* __restrict__ rowstart, int* __restrict__ cursor,
                            int* __restrict__ csr) {
    int e = blockIdx.x * 256 + threadIdx.x;
    if (e >= NE) return;
    int d = dst[e];
    int pos = rowstart[d] + atomicAdd(&cursor[d], 1);
    csr[pos] = src[e];
}

__global__ void dinv_kernel(const int* __restrict__ counts, float* __restrict__ dinv) {
    int n = blockIdx.x * 256 + threadIdx.x;
    if (n < NN) dinv[n] = rsqrtf((float)counts[n] + 1.0f);
}

// ---------------------------------------------------------------------------
// Weight prep: Wt[n][k] = bf16(W[k][n]); all four layers in one launch.
// Layout in Wt (ushort): Wt1 [128][128] @0, Wt2 @16384, Wt3 @32768, Wt4 [64][128] @49152
// ---------------------------------------------------------------------------
__global__ void wconv_kernel(const float* __restrict__ W1, const float* __restrict__ W2,
                             const float* __restrict__ W3, const float* __restrict__ W4,
                             ushort* __restrict__ Wt) {
    int id = blockIdx.x * 256 + threadIdx.x;
    if (id < 49152) {
        int l = id / 16384, r = id % 16384;
        int n = r >> 7, k = r & 127;
        const float* W = (l == 0) ? W1 : (l == 1) ? W2 : W3;
        Wt[l * 16384 + n * 128 + k] = f2bf(W[k * 128 + n]);
    } else if (id < 57344) {
        int r = id - 49152;
        int n = r >> 7, k = r & 127;
        Wt[49152 + n * 128 + k] = f2bf(W4[k * 64 + n]);
    }
}

// ---------------------------------------------------------------------------
// MFMA GEMM: U(bf16) = bf16( relu?(X*sc+sh) @ W ) * dinv[row]
// X: fp32 [NN][128] (pre-BN activations), Wt: bf16 [F][128] (transposed)
// Block: 256 thr (4 waves), 64 rows x F cols. K = 128 in 4 steps of 32.
// LDS stride 136 bf16: 16B-aligned, bank-even for ds_read_b128.
// ---------------------------------------------------------------------------
template<int F, bool BN>
__global__ __launch_bounds__(256) void gemm_bf16_kernel(
    const float* __restrict__ X, const ushort* __restrict__ Wt,
    const float* __restrict__ dinv, const float* __restrict__ sc,
    const float* __restrict__ sh, ushort* __restrict__ U)
{
    constexpr int NT  = F / 16;   // col tiles per wave
    constexpr int LDK = 136;
    __shared__ __align__(16) ushort Xs[64 * LDK];
    __shared__ __align__(16) ushort Ws[F * LDK];

    const int tid  = threadIdx.x;
    const int wave = tid >> 6;
    const int lane = tid & 63;
    const int row0 = blockIdx.x * 64;

    // stage Wt -> LDS, 16B chunks
#pragma unroll
    for (int it = 0; it < F / 16; it++) {
        int idx = it * 256 + tid;
        int n   = idx >> 4;
        int k8  = (idx & 15) * 8;
        *(uint4*)&Ws[n * LDK + k8] = *(const uint4*)&Wt[n * 128 + k8];
    }
    // stage X (+BN+ReLU) -> bf16 LDS
#pragma unroll
    for (int it = 0; it < 8; it++) {
        int idx = it * 256 + tid;
        int r   = idx >> 5;
        int c4  = (idx & 31) * 4;
        int row = row0 + r;
        float4 v = make_float4(0.f, 0.f, 0.f, 0.f);
        if (row < NN) v = *(const float4*)&X[(size_t)row * 128 + c4];
        if constexpr (BN) {
            float4 s = *(const float4*)&sc[c4];
            float4 h = *(const float4*)&sh[c4];
            v.x = fmaxf(0.f, v.x * s.x + h.x);
            v.y = fmaxf(0.f, v.y * s.y + h.y);
            v.z = fmaxf(0.f, v.z * s.z + h.z);
            v.w = fmaxf(0.f, v.w * s.w + h.w);
        }
        ushort4 o;
        o.x = f2bf(v.x); o.y = f2bf(v.y); o.z = f2bf(v.z); o.w = f2bf(v.w);
        *(ushort4*)&Xs[r * LDK + c4] = o;
    }
    __syncthreads();

    f32x4 acc[NT];
#pragma unroll
    for (int nt = 0; nt < NT; nt++) acc[nt] = (f32x4){0.f, 0.f, 0.f, 0.f};

    const int m = lane & 15;
    const int q = lane >> 4;
#pragma unroll
    for (int k0 = 0; k0 < 128; k0 += 32) {
        bf16x8 a = *(const bf16x8*)&Xs[(wave * 16 + m) * LDK + k0 + q * 8];
#pragma unroll
        for (int nt = 0; nt < NT; nt++) {
            bf16x8 b = *(const bf16x8*)&Ws[(nt * 16 + m) * LDK + k0 + q * 8];
            acc[nt] = __builtin_amdgcn_mfma_f32_16x16x32_bf16(a, b, acc[nt], 0, 0, 0);
        }
    }

    // epilogue: C[row][col], col = m (within tile), row = q*4 + r
#pragma unroll
    for (int r = 0; r < 4; r++) {
        int row = row0 + wave * 16 + q * 4 + r;
        if (row < NN) {
            float di = dinv[row];
#pragma unroll
            for (int nt = 0; nt < NT; nt++) {
                U[(size_t)row * F + nt * 16 + m] = f2bf(acc[nt][r] * di);
            }
        }
    }
}

// ---------------------------------------------------------------------------
// Gather (atomic-free) + fused BN stats. Wave per node (grid-stride).
// Y[n] = dinv[n] * (sum_{e->n} U[src] + U[n]) + b  (fp32 out, U is bf16)
// ---------------------------------------------------------------------------
__global__ __launch_bounds__(256) void gather128_kernel(
    const int* __restrict__ csr, const int* __restrict__ rowst,
    const int* __restrict__ counts, const ushort* __restrict__ U,
    const float* __restrict__ dinv, const float* __restrict__ b,
    float* __restrict__ Y, float* __restrict__ sums, float* __restrict__ sumsq)
{
    __shared__ float ssum[128], ssq[128];
    if (threadIdx.x < 128) { ssum[threadIdx.x] = 0.f; ssq[threadIdx.x] = 0.f; }
    __syncthreads();

    const int lane   = threadIdx.x & 63;
    const int waveId = (blockIdx.x * 256 + threadIdx.x) >> 6;
    const int nWaves = gridDim.x * 4;
    const int coff   = lane * 2;

    float bx = b[coff], by = b[coff + 1];
    float s0 = 0.f, s1 = 0.f, q0 = 0.f, q1 = 0.f;

    for (int n = waveId; n < NN; n += nWaves) {
        int base = rowst[n];
        int deg  = counts[n];
        float ax = 0.f, ay = 0.f;
        int j = 0;
        for (; j + 4 <= deg; j += 4) {
            int e0 = csr[base + j + 0];
            int e1 = csr[base + j + 1];
            int e2 = csr[base + j + 2];
            int e3 = csr[base + j + 3];
            unsigned u0 = *(const unsigned*)&U[(size_t)e0 * 128 + coff];
            unsigned u1 = *(const unsigned*)&U[(size_t)e1 * 128 + coff];
            unsigned u2 = *(const unsigned*)&U[(size_t)e2 * 128 + coff];
            unsigned u3 = *(const unsigned*)&U[(size_t)e3 * 128 + coff];
            ax += bflo(u0) + bflo(u1) + bflo(u2) + bflo(u3);
            ay += bfhi(u0) + bfhi(u1) + bfhi(u2) + bfhi(u3);
        }
        for (; j < deg; j++) {
            int e = csr[base + j];
            unsigned u = *(const unsigned*)&U[(size_t)e * 128 + coff];
            ax += bflo(u); ay += bfhi(u);
        }
        unsigned us = *(const unsigned*)&U[(size_t)n * 128 + coff];
        float di = dinv[n];
        float ox = di * (ax + bflo(us)) + bx;
        float oy = di * (ay + bfhi(us)) + by;
        *(float2*)&Y[(size_t)n * 128 + coff] = make_float2(ox, oy);
        s0 += ox; q0 += ox * ox;
        s1 += oy; q1 += oy * oy;
    }

    atomicAdd(&ssum[coff], s0);     atomicAdd(&ssum[coff + 1], s1);
    atomicAdd(&ssq[coff], q0);      atomicAdd(&ssq[coff + 1], q1);
    __syncthreads();
    if (threadIdx.x < 128) {
        atomicAdd(&sums[threadIdx.x],  ssum[threadIdx.x]);
        atomicAdd(&sumsq[threadIdx.x], ssq[threadIdx.x]);
    }
}

__global__ __launch_bounds__(256) void gather64_kernel(
    const int* __restrict__ csr, const int* __restrict__ rowst,
    const int* __restrict__ counts, const ushort* __restrict__ U,
    const float* __restrict__ dinv, const float* __restrict__ b,
    float* __restrict__ Y)
{
    const int lane   = threadIdx.x & 63;
    const int waveId = (blockIdx.x * 256 + threadIdx.x) >> 6;
    const int nWaves = gridDim.x * 4;
    float bl_ = b[lane];

    for (int n = waveId; n < NN; n += nWaves) {
        int base = rowst[n];
        int deg  = counts[n];
        float a = 0.f;
        int j = 0;
        for (; j + 4 <= deg; j += 4) {
            int e0 = csr[base + j + 0];
            int e1 = csr[base + j + 1];
            int e2 = csr[base + j + 2];
            int e3 = csr[base + j + 3];
            a += bflo(U[(size_t)e0 * 64 + lane]) + bflo(U[(size_t)e1 * 64 + lane])
               + bflo(U[(size_t)e2 * 64 + lane]) + bflo(U[(size_t)e3 * 64 + lane]);
        }
        for (; j < deg; j++) {
            int e = csr[base + j];
            a += bflo(U[(size_t)e * 64 + lane]);
        }
        float self = bflo(U[(size_t)n * 64 + lane]);
        Y[(size_t)n * 64 + lane] = dinv[n] * (a + self) + bl_;
    }
}

// ---------------------------------------------------------------------------
// BN prep: sums/sumsq -> sc/sh, then re-zero sums/sumsq for next layer.
// ---------------------------------------------------------------------------
__global__ void bn_prep_kernel(float* __restrict__ sums, float* __restrict__ sumsq,
                               const float* __restrict__ g, const float* __restrict__ be,
                               float* __restrict__ sc, float* __restrict__ sh)
{
    int c = threadIdx.x;
    float mu  = sums[c] * (1.0f / NN);
    float var = sumsq[c] * (1.0f / NN) - mu * mu;
    float s   = rsqrtf(var + EPS) * g[c];
    sc[c] = s;
    sh[c] = be[c] - mu * s;
    sums[c]  = 0.f;
    sumsq[c] = 0.f;
}

// ---------------------------------------------------------------------------
extern "C" void kernel_launch(void* const* d_in, const int* in_sizes, int n_in,
                              void* d_out, int out_size, void* d_ws, size_t ws_size,
                              hipStream_t stream)
{
    const float* x   = (const float*)d_in[0];
    const int*   ei  = (const int*)d_in[1];
    const int*   src = ei;
    const int*   dst = ei + NE;
    const float* W1 = (const float*)d_in[2];  const float* b1 = (const float*)d_in[3];
    const float* W2 = (const float*)d_in[4];  const float* b2 = (const float*)d_in[5];
    const float* W3 = (const float*)d_in[6];  const float* b3 = (const float*)d_in[7];
    const float* W4 = (const float*)d_in[8];  const float* b4 = (const float*)d_in[9];
    const float* g1 = (const float*)d_in[10]; const float* be1 = (const float*)d_in[11];
    const float* g2 = (const float*)d_in[12]; const float* be2 = (const float*)d_in[13];
    const float* g3 = (const float*)d_in[14]; const float* be3 = (const float*)d_in[15];
    float* out = (float*)d_out;

    // workspace layout (~42.5 MB)
    char* wsb = (char*)d_ws;
    float* dinv   = (float*)wsb;                    // NN f
    int*   counts = (int*)(dinv + NN);              // NN i   (counts+cursor: one memset)
    int*   cursor = counts + NN;                    // NN i
    int*   rowst  = cursor + NN;                    // NN i
    int*   bsum   = rowst + NN;                     // 256 i
    float* sums   = (float*)(bsum + 256);           // 128 f  (sums+sumsq: one memset)
    float* sumsq  = sums + 128;                     // 128 f
    float* sc     = sumsq + 128;                    // 128 f
    float* sh     = sc + 128;                       // 128 f
    ushort* Wt    = (ushort*)(sh + 128);            // 57344 ushorts (16B-aligned)
    int*   csr    = (int*)(Wt + 57344);             // NE i
    float* Y      = (float*)(csr + NE);             // NN*128 f
    ushort* U     = (ushort*)(Y + (size_t)NN * 128);// NN*128 bf16

    const ushort* Wt1 = Wt;
    const ushort* Wt2 = Wt + 16384;
    const ushort* Wt3 = Wt + 32768;
    const ushort* Wt4 = Wt + 49152;

    const int edgeGrid = (NE + 255) / 256;
    const int gemmGrid = (NN + 63) / 64;
    const int gathGrid = 960;

    // ---- prep: CSR + dinv + weights + zeroed stats
    hipMemsetAsync(counts, 0, 2 * NN * sizeof(int), stream);     // counts+cursor
    hipMemsetAsync(sums, 0, 256 * sizeof(float), stream);        // sums+sumsq
    hist_kernel<<<edgeGrid, 256, 0, stream>>>(dst, counts);
    blocksum_kernel<<<SCAN_NB, SCAN_BS, 0, stream>>>(counts, bsum);
    scanbsum_kernel<<<1, SCAN_BS, 0, stream>>>(bsum);
    scanfinal_kernel<<<SCAN_NB, SCAN_BS, 0, stream>>>(counts, bsum, rowst);
    fill_kernel<<<edgeGrid, 256, 0, stream>>>(src, dst, rowst, cursor, csr);
    dinv_kernel<<<(NN + 255) / 256, 256, 0, stream>>>(counts, dinv);
    wconv_kernel<<<(57344 + 255) / 256, 256, 0, stream>>>(W1, W2, W3, W4, Wt);

    // ---- Layer 1
    gemm_bf16_kernel<128, false><<<gemmGrid, 256, 0, stream>>>(x, Wt1, dinv, sc, sh, U);
    gather128_kernel<<<gathGrid, 256, 0, stream>>>(csr, rowst, counts, U, dinv, b1, Y, sums, sumsq);
    bn_prep_kernel<<<1, 128, 0, stream>>>(sums, sumsq, g1, be1, sc, sh);

    // ---- Layer 2
    gemm_bf16_kernel<128, true><<<gemmGrid, 256, 0, stream>>>(Y, Wt2, dinv, sc, sh, U);
    gather128_kernel<<<gathGrid, 256, 0, stream>>>(csr, rowst, counts, U, dinv, b2, Y, sums, sumsq);
    bn_prep_kernel<<<1, 128, 0, stream>>>(sums, sumsq, g2, be2, sc, sh);

    // ---- Layer 3
    gemm_bf16_kernel<128, true><<<gemmGrid, 256, 0, stream>>>(Y, Wt3, dinv, sc, sh, U);
    gather128_kernel<<<gathGrid, 256, 0, stream>>>(csr, rowst, counts, U, dinv, b3, Y, sums, sumsq);
    bn_prep_kernel<<<1, 128, 0, stream>>>(sums, sumsq, g3, be3, sc, sh);

    // ---- Layer 4 (no BN stats; gather straight to d_out)
    gemm_bf16_kernel<64, true><<<gemmGrid, 256, 0, stream>>>(Y, Wt4, dinv, sc, sh, U);
    gather64_kernel<<<gathGrid, 256, 0, stream>>>(csr, rowst, counts, U, dinv, b4, out);
}